// Round 10
// baseline (92.805 us; speedup 1.0000x reference)
//
#include <hip/hip_runtime.h>

// Problem constants: x [32,112,112,128] fp32, W [7,7,2,1] HWIO, b [1]
static constexpr int Bn = 32;
static constexpr int Hn = 112;
static constexpr int Wn = 112;
static constexpr int HALO = 3;
static constexpr int PAIRS_PER_IMG = Hn / 2;   // 56
static constexpr int NPAIR = Bn * PAIRS_PER_IMG;  // 1792 blocks, block = 2 rows
static constexpr int SPIN_MAX = 150;

typedef float floatx4 __attribute__((ext_vector_type(4)));

union f2u { float2 f; unsigned long long u; };

// ---------------------------------------------------------------------------
// Row-PAIR producer-consumer fused kernel (R9 structure, 2 rows/block).
// Block = (image b, pair s) -> rows r0=2s, r1=2s+1. 512 threads = 16 groups
// of 32 lanes; groups 0-7 own row r0, groups 8-15 own row r1 (group g covers
// columns (g&7)+8j, j=0..13 -> 14 float4/thread, same payload as R9).
//
//  P0: both rows' x -> registers (issued first).
//  P1: stats from regs -> LDS rows 3,4 + global (relaxed u64, no fences);
//      pin regs with asm; vmcnt(0)+barrier; publish ONE flag per pair.
//  P2: spin on 4 neighbor-pair flags (vs 6 row-flags in R9); timeout ->
//      recompute that row from x (identical values, any-schedule-correct).
//  P3: conv+sigmoid: 224 threads, one per output pixel (2 rows x 112).
//  P4: out = x(reg) * gate, NT store.
//
// Halo map (sdat row k = image row 2s-3+k, k=0..7):
//   k=0 -> pair s-2 | k=1,2 -> s-1 | k=3,4 -> own | k=5,6 -> s+1 | k=7 -> s+2
// ---------------------------------------------------------------------------
__global__ __launch_bounds__(512) void fused_pair_kernel(const float* __restrict__ x,
                                                         const float* __restrict__ Wc,
                                                         const float* __restrict__ bias,
                                                         unsigned long long* __restrict__ stats,
                                                         int* __restrict__ flags,
                                                         float* __restrict__ out) {
    __shared__ float2 sdat[8][Wn + 2 * HALO];  // 8 x 118 float2 (7.6 KB), zero-padded
    __shared__ float  glds[2][Wn];
    __shared__ float  w[98];
    __shared__ int    rowstate[8];             // 0=own,1=from global,2=zero,3=recompute

    const int wid  = blockIdx.x;               // pair id = b*56 + s
    const int b    = wid / PAIRS_PER_IMG;
    const int s    = wid % PAIRS_PER_IMG;
    const int r0   = 2 * s;
    const int tid  = threadIdx.x;
    const int lane = tid & 31;
    const int grp  = tid >> 5;                 // 16 groups
    const int gRow = grp >> 3;                 // 0 or 1 (own row within pair)
    const int gCol = grp & 7;

    const floatx4* __restrict__ x4 = reinterpret_cast<const floatx4*>(x);
    const size_t rowbase = ((size_t)(b * Hn + r0 + gRow)) * Wn * 32;   // float4 units

    // ---- P0: own-row x -> registers (issued first, hides HBM latency) -----
    float xa[14], xb[14], xc[14], xd[14];
#pragma unroll
    for (int j = 0; j < 14; ++j) {
        const int c = gCol + 8 * j;
        const floatx4 v = x4[rowbase + (size_t)c * 32 + lane];
        xa[j] = v.x; xb[j] = v.y; xc[j] = v.z; xd[j] = v.w;
    }

    if (tid < 98) w[tid] = Wc[tid];
    for (int i = tid; i < 8 * (Wn + 2 * HALO); i += 512)
        ((float2*)sdat)[i] = make_float2(0.f, 0.f);
    __syncthreads();

    // ---- P1: own-row stats from regs -> LDS + global (relaxed) ------------
    const size_t myStatRow = (size_t)(b * Hn + r0 + gRow) * Wn;
#pragma unroll
    for (int j = 0; j < 14; ++j) {
        const int c = gCol + 8 * j;
        float sm = xa[j] + xb[j] + xc[j] + xd[j];
        float mx = fmaxf(fmaxf(xa[j], xb[j]), fmaxf(xc[j], xd[j]));
#pragma unroll
        for (int off = 16; off >= 1; off >>= 1) {
            sm += __shfl_xor(sm, off);
            mx = fmaxf(mx, __shfl_xor(mx, off));
        }
        if (lane == 0) {
            f2u t; t.f = make_float2(sm * (1.0f / 128.0f), mx);
            sdat[3 + gRow][c + HALO] = t.f;
            __hip_atomic_store(&stats[myStatRow + c], t.u,
                               __ATOMIC_RELAXED, __HIP_MEMORY_SCOPE_AGENT);
        }
    }

    // Pin x in registers (compiler may park in AGPRs; no memory traffic).
#pragma unroll
    for (int j = 0; j < 14; ++j)
        asm volatile("" : "+v"(xa[j]), "+v"(xb[j]), "+v"(xc[j]), "+v"(xd[j]));

    asm volatile("s_waitcnt vmcnt(0)" ::: "memory");     // stats stores done
    __syncthreads();
    if (tid == 0)
        __hip_atomic_store(&flags[wid], 1, __ATOMIC_RELAXED, __HIP_MEMORY_SCOPE_AGENT);

    // ---- P2a: bounded spin on neighbor-pair flags (k = sdat row 0..7) ------
    if (tid < 8) {
        const int k = tid;
        int st;
        if (k == 3 || k == 4) st = 0;                    // own rows
        else {
            const int rr = r0 - HALO + k;                // image row
            if (rr < 0 || rr >= Hn) st = 2;              // zero padding
            else {
                const int ps = s + ((k < 3) ? ((k == 0) ? -2 : -1)
                                            : ((k == 7) ? 2 : 1));
                const int f = b * PAIRS_PER_IMG + ps;
                int it = 0, got = 0;
                do {
                    got = __hip_atomic_load(&flags[f], __ATOMIC_RELAXED,
                                            __HIP_MEMORY_SCOPE_AGENT);
                } while (!got && ++it < SPIN_MAX);
                st = got ? 1 : 3;
            }
        }
        rowstate[k] = st;
    }
    __syncthreads();

    // ---- P2b: bulk-load published halo stats (relaxed u64 from MALL) -------
    for (int p = tid; p < 8 * Wn; p += 512) {
        const int k = p / Wn;
        const int c = p % Wn;
        if (rowstate[k] == 1) {
            const int rr = r0 - HALO + k;
            f2u t;
            t.u = __hip_atomic_load(&stats[(size_t)(b * Hn + rr) * Wn + c],
                                    __ATOMIC_RELAXED, __HIP_MEMORY_SCOPE_AGENT);
            sdat[k][c + HALO] = t.f;
        }
    }
    // ---- P2c: fallback recompute for unpublished rows (rare, correct) ------
    for (int k = 0; k < 8; ++k) {
        if (rowstate[k] != 3) continue;                  // uniform across block
        const int rr = r0 - HALO + k;
        const size_t rb = ((size_t)(b * Hn + rr)) * Wn * 32;
        for (int pc = grp; pc < Wn; pc += 16) {
            const floatx4 v = x4[rb + (size_t)pc * 32 + lane];
            float sm = v.x + v.y + v.z + v.w;
            float mx = fmaxf(fmaxf(v.x, v.y), fmaxf(v.z, v.w));
#pragma unroll
            for (int off = 16; off >= 1; off >>= 1) {
                sm += __shfl_xor(sm, off);
                mx = fmaxf(mx, __shfl_xor(mx, off));
            }
            if (lane == 0) sdat[k][pc + HALO] = make_float2(sm * (1.0f / 128.0f), mx);
        }
    }
    __syncthreads();

    // ---- P3: conv + bias + sigmoid, one thread per output pixel (224) ------
    if (tid < 2 * Wn) {
        const int row = tid / Wn;                        // 0 or 1
        const int c   = tid % Wn;
        float acc = bias[0];
#pragma unroll
        for (int kh = 0; kh < 7; ++kh)
#pragma unroll
            for (int kw = 0; kw < 7; ++kw) {
                const float2 sv = sdat[row + kh][c + kw];
                acc = fmaf(sv.x, w[(kh * 7 + kw) * 2 + 0], acc);
                acc = fmaf(sv.y, w[(kh * 7 + kw) * 2 + 1], acc);
            }
        glds[row][c] = 1.0f / (1.0f + expf(-acc));
    }
    __syncthreads();

    // ---- P4: out = x(reg) * gate, NT store ---------------------------------
    floatx4* __restrict__ o4 = reinterpret_cast<floatx4*>(out);
#pragma unroll
    for (int j = 0; j < 14; ++j) {
        const int c = gCol + 8 * j;
        const float g = glds[gRow][c];
        floatx4 v;
        v.x = xa[j] * g; v.y = xb[j] * g; v.z = xc[j] * g; v.w = xd[j] * g;
        __builtin_nontemporal_store(v, &o4[rowbase + (size_t)c * 32 + lane]);
    }
}

extern "C" void kernel_launch(void* const* d_in, const int* in_sizes, int n_in,
                              void* d_out, int out_size, void* d_ws, size_t ws_size,
                              hipStream_t stream) {
    const float* x  = (const float*)d_in[0];
    const float* Wc = (const float*)d_in[1];
    const float* bb = (const float*)d_in[2];
    float* out = (float*)d_out;

    // workspace: stats u64[NROWS*Wn] (3.2 MB) then flags int[NPAIR] (7 KB)
    unsigned long long* stats = (unsigned long long*)d_ws;
    int* flags = (int*)((char*)d_ws + (size_t)Bn * Hn * Wn * sizeof(unsigned long long));

    hipMemsetAsync(flags, 0, NPAIR * sizeof(int), stream);
    fused_pair_kernel<<<NPAIR, 512, 0, stream>>>(x, Wc, bb, stats, flags, out);
}

// Round 11
// 90.451 us; speedup vs baseline: 1.0260x; 1.0260x over previous
//
#include <hip/hip_runtime.h>

// Problem constants: x [32,112,112,128] fp32, W [7,7,2,1] HWIO, b [1]
static constexpr int Bn = 32;
static constexpr int Hn = 112;
static constexpr int Wn = 112;
static constexpr int HW  = 56;                 // half-row width
static constexpr int HALO = 3;
static constexpr int NHALF = Bn * Hn * 2;      // 7168 blocks, block = half row
static constexpr int SPIN_MAX = 200;

typedef float floatx4 __attribute__((ext_vector_type(4)));

union f2u { float2 f; unsigned long long u; };

// ---------------------------------------------------------------------------
// HALF-ROW producer-consumer fused kernel. R9's structure at 2x finer grain:
// 28 payload floats/thread (vs 56) -> ~76 regs -> 6 waves/SIMD (~75% occ)
// -> 6 co-resident blocks/CU for phase overlap (R10 showed occupancy is the
// operative variable: coarser blocks -> 41% occ -> regression).
//
// Block = (row id, half h). Covers cols c0..c0+55, c0 = h*56.
//  P0: own half-row x -> regs (7 float4/thread).
//  P1: stats -> LDS + global (relaxed u64); pin regs; vmcnt(0)+barrier; flag.
//  P2: spin on the 14 (row r-3..r+3, half) flags of the 7x62 stat window;
//      timeout -> recompute that half-row from x (identical values).
//  P3: conv+sigmoid for 56 pixels.
//  P4: out = x(reg) * gate, NT store.
// ---------------------------------------------------------------------------
__global__ __launch_bounds__(256) void fused_half_kernel(const float* __restrict__ x,
                                                         const float* __restrict__ Wc,
                                                         const float* __restrict__ bias,
                                                         unsigned long long* __restrict__ stats,
                                                         int* __restrict__ flags,
                                                         float* __restrict__ out) {
    __shared__ float2 sdat[7][HW + 2 * HALO];  // 7 x 62 float2 (3.5 KB); col 0 = image col c0-3
    __shared__ float  glds[HW];
    __shared__ float  w[98];
    __shared__ int    rowstate[14];            // (k,half): 0=own,1=global,2=zero,3=recompute

    const int wid   = blockIdx.x;
    const int h     = wid & 1;
    const int rowid = wid >> 1;                // b*Hn + r
    const int b     = rowid / Hn;
    const int r     = rowid % Hn;
    const int c0    = h * HW;
    const int tid   = threadIdx.x;
    const int lane  = tid & 31;
    const int grp   = tid >> 5;                // 8 groups; group = one pixel (32 float4)

    const floatx4* __restrict__ x4 = reinterpret_cast<const floatx4*>(x);
    const size_t rowbase = (size_t)rowid * Wn * 32;      // float4 units

    // ---- P0: own half-row x -> registers ----------------------------------
    float xa[7], xb[7], xc[7], xd[7];
#pragma unroll
    for (int j = 0; j < 7; ++j) {
        const int c = c0 + grp + 8 * j;
        const floatx4 v = x4[rowbase + (size_t)c * 32 + lane];
        xa[j] = v.x; xb[j] = v.y; xc[j] = v.z; xd[j] = v.w;
    }

    if (tid < 98) w[tid] = Wc[tid];
    for (int i = tid; i < 7 * (HW + 2 * HALO); i += 256)
        ((float2*)sdat)[i] = make_float2(0.f, 0.f);
    __syncthreads();

    // ---- P1: stats from regs -> LDS + global (relaxed) --------------------
#pragma unroll
    for (int j = 0; j < 7; ++j) {
        const int c = c0 + grp + 8 * j;                  // image col
        float sm = xa[j] + xb[j] + xc[j] + xd[j];
        float mx = fmaxf(fmaxf(xa[j], xb[j]), fmaxf(xc[j], xd[j]));
#pragma unroll
        for (int off = 16; off >= 1; off >>= 1) {
            sm += __shfl_xor(sm, off);
            mx = fmaxf(mx, __shfl_xor(mx, off));
        }
        if (lane == 0) {
            f2u t; t.f = make_float2(sm * (1.0f / 128.0f), mx);
            sdat[HALO][c - c0 + HALO] = t.f;             // idx 3..58
            __hip_atomic_store(&stats[(size_t)rowid * Wn + c], t.u,
                               __ATOMIC_RELAXED, __HIP_MEMORY_SCOPE_AGENT);
        }
    }

    // Pin payload in registers (no rematerialization from memory).
#pragma unroll
    for (int j = 0; j < 7; ++j)
        asm volatile("" : "+v"(xa[j]), "+v"(xb[j]), "+v"(xc[j]), "+v"(xd[j]));

    asm volatile("s_waitcnt vmcnt(0)" ::: "memory");
    __syncthreads();
    if (tid == 0)
        __hip_atomic_store(&flags[wid], 1, __ATOMIC_RELAXED, __HIP_MEMORY_SCOPE_AGENT);

    // ---- P2a: bounded spin on 14 (row,half) flags --------------------------
    if (tid < 14) {
        const int k  = tid >> 1;                         // 0..6
        const int hh = tid & 1;
        int st;
        const int rr = r - HALO + k;
        if (k == HALO && hh == h) st = 0;                // own half-row
        else if (rr < 0 || rr >= Hn) st = 2;             // zero padding
        else {
            const int f = ((b * Hn + rr) << 1) | hh;
            int it = 0, got = 0;
            do {
                got = __hip_atomic_load(&flags[f], __ATOMIC_RELAXED,
                                        __HIP_MEMORY_SCOPE_AGENT);
            } while (!got && ++it < SPIN_MAX);
            st = got ? 1 : 3;
        }
        rowstate[tid] = st;
    }
    __syncthreads();

    // ---- P2b: load published stats for the 7x62 window ---------------------
    for (int p = tid; p < 7 * (HW + 2 * HALO); p += 256) {
        const int k  = p / (HW + 2 * HALO);
        const int cc = p % (HW + 2 * HALO);
        const int c  = c0 - HALO + cc;                   // image col
        if (c < 0 || c >= Wn) continue;                  // stays zero
        const int hh = c / HW;
        if (rowstate[k * 2 + hh] == 1) {
            const int rr = r - HALO + k;
            f2u t;
            t.u = __hip_atomic_load(&stats[(size_t)(b * Hn + rr) * Wn + c],
                                    __ATOMIC_RELAXED, __HIP_MEMORY_SCOPE_AGENT);
            sdat[k][cc] = t.f;
        }
    }
    // ---- P2c: fallback recompute (rare; identical values, schedule-safe) ---
    for (int q = 0; q < 14; ++q) {
        if (rowstate[q] != 3) continue;                  // uniform across block
        const int k  = q >> 1;
        const int hh = q & 1;
        const int rr = r - HALO + k;
        const size_t rb = (size_t)(b * Hn + rr) * Wn * 32;
        for (int pc = grp; pc < HW; pc += 8) {
            const int c = hh * HW + pc;                  // image col
            const floatx4 v = x4[rb + (size_t)c * 32 + lane];
            float sm = v.x + v.y + v.z + v.w;
            float mx = fmaxf(fmaxf(v.x, v.y), fmaxf(v.z, v.w));
#pragma unroll
            for (int off = 16; off >= 1; off >>= 1) {
                sm += __shfl_xor(sm, off);
                mx = fmaxf(mx, __shfl_xor(mx, off));
            }
            const int idx = c - (c0 - HALO);
            if (lane == 0 && idx >= 0 && idx < HW + 2 * HALO)
                sdat[k][idx] = make_float2(sm * (1.0f / 128.0f), mx);
        }
    }
    __syncthreads();

    // ---- P3: 7x7 conv + bias + sigmoid -> gate ------------------------------
    if (tid < HW) {
        float acc = bias[0];
#pragma unroll
        for (int kh = 0; kh < 7; ++kh)
#pragma unroll
            for (int kw = 0; kw < 7; ++kw) {
                const float2 sv = sdat[kh][tid + kw];
                acc = fmaf(sv.x, w[(kh * 7 + kw) * 2 + 0], acc);
                acc = fmaf(sv.y, w[(kh * 7 + kw) * 2 + 1], acc);
            }
        glds[tid] = 1.0f / (1.0f + expf(-acc));
    }
    __syncthreads();

    // ---- P4: out = x(reg) * gate, NT store ---------------------------------
    floatx4* __restrict__ o4 = reinterpret_cast<floatx4*>(out);
#pragma unroll
    for (int j = 0; j < 7; ++j) {
        const int cl = grp + 8 * j;                      // local col 0..55
        const float g = glds[cl];
        floatx4 v;
        v.x = xa[j] * g; v.y = xb[j] * g; v.z = xc[j] * g; v.w = xd[j] * g;
        __builtin_nontemporal_store(v, &o4[rowbase + (size_t)(c0 + cl) * 32 + lane]);
    }
}

extern "C" void kernel_launch(void* const* d_in, const int* in_sizes, int n_in,
                              void* d_out, int out_size, void* d_ws, size_t ws_size,
                              hipStream_t stream) {
    const float* x  = (const float*)d_in[0];
    const float* Wc = (const float*)d_in[1];
    const float* bb = (const float*)d_in[2];
    float* out = (float*)d_out;

    // workspace: stats u64[Bn*Hn*Wn] (3.2 MB) then flags int[NHALF] (28 KB)
    unsigned long long* stats = (unsigned long long*)d_ws;
    int* flags = (int*)((char*)d_ws + (size_t)Bn * Hn * Wn * sizeof(unsigned long long));

    hipMemsetAsync(flags, 0, NHALF * sizeof(int), stream);
    fused_half_kernel<<<NHALF, 256, 0, stream>>>(x, Wc, bb, stats, flags, out);
}

// Round 12
// 85.091 us; speedup vs baseline: 1.0907x; 1.0630x over previous
//
#include <hip/hip_runtime.h>

// Problem constants: x [32,112,112,128] fp32, W [7,7,2,1] HWIO, b [1]
static constexpr int Bn = 32;
static constexpr int Hn = 112;
static constexpr int Wn = 112;
static constexpr int HALO = 3;
static constexpr int NROWS = Bn * Hn;          // 3584 blocks, block = one image row
static constexpr int SPIN_MAX = 100;           // with s_sleep(16): ~40us, then fallback

typedef float floatx4 __attribute__((ext_vector_type(4)));

union f2u { float2 f; unsigned long long u; };

// ---------------------------------------------------------------------------
// R9 structure (best: 88.3us) with ONE change: the flag spin uses
// first-check-then-s_sleep(16) backoff instead of a tight poll loop.
// R11's occupancy experiment (81% occ, 90.5us) refuted the occupancy
// hypothesis; the revised model is that tight-loop relaxed polls (MALL
// round trips) flood the fabric and burn SIMD issue slots. Backoff cuts
// poll traffic ~30x and yields the SIMD to co-resident blocks.
//
//  P0: own-row x -> registers (14 float4/thread), issued first.
//  P1: stats (mean,max over 128ch) from regs -> LDS + global via RELAXED
//      agent-scope u64 stores (straight to MALL, no cache maintenance);
//      pin regs with asm; s_waitcnt vmcnt(0) + barrier; publish flag.
//  P2: spin with backoff on 6 neighbor flags; timeout -> recompute row
//      from x (identical values => correct under any dispatch schedule).
//  P3: 7x7x2 conv + bias + sigmoid -> gate in LDS.
//  P4: out = x(reg) * gate, non-temporal store. x never re-read.
// ---------------------------------------------------------------------------
__global__ __launch_bounds__(256) void fused_reg_kernel(const float* __restrict__ x,
                                                        const float* __restrict__ Wc,
                                                        const float* __restrict__ bias,
                                                        unsigned long long* __restrict__ stats,
                                                        int* __restrict__ flags,
                                                        float* __restrict__ out) {
    __shared__ float2 sdat[7][Wn + 2 * HALO];  // zero-padded stat tile (6.6 KB)
    __shared__ float  glds[Wn];
    __shared__ float  w[98];
    __shared__ int    rowstate[7];             // 0=own,1=from global,2=zero,3=recompute

    const int wid  = blockIdx.x;               // == b*Hn + r
    const int b    = wid / Hn;
    const int r    = wid % Hn;
    const int tid  = threadIdx.x;
    const int lane = tid & 31;
    const int grp  = tid >> 5;                 // 8 groups; group = one pixel (32 float4)

    const floatx4* __restrict__ x4 = reinterpret_cast<const floatx4*>(x);
    const size_t rowbase = (size_t)wid * Wn * 32;        // float4 units

    // ---- P0: own-row x -> registers (issued first, hides HBM latency) -----
    float xa[14], xb[14], xc[14], xd[14];
#pragma unroll
    for (int j = 0; j < 14; ++j) {
        const int c = grp + 8 * j;
        const floatx4 v = x4[rowbase + (size_t)c * 32 + lane];
        xa[j] = v.x; xb[j] = v.y; xc[j] = v.z; xd[j] = v.w;
    }

    if (tid < 98) w[tid] = Wc[tid];
    for (int i = tid; i < 7 * (Wn + 2 * HALO); i += 256)
        ((float2*)sdat)[i] = make_float2(0.f, 0.f);
    __syncthreads();

    // ---- P1: own-row stats from registers -> LDS + global (relaxed) -------
#pragma unroll
    for (int j = 0; j < 14; ++j) {
        const int c = grp + 8 * j;
        float s = xa[j] + xb[j] + xc[j] + xd[j];
        float m = fmaxf(fmaxf(xa[j], xb[j]), fmaxf(xc[j], xd[j]));
#pragma unroll
        for (int off = 16; off >= 1; off >>= 1) {
            s += __shfl_xor(s, off);
            m = fmaxf(m, __shfl_xor(m, off));
        }
        if (lane == 0) {
            f2u t; t.f = make_float2(s * (1.0f / 128.0f), m);
            sdat[HALO][c + HALO] = t.f;
            __hip_atomic_store(&stats[(size_t)wid * Wn + c], t.u,
                               __ATOMIC_RELAXED, __HIP_MEMORY_SCOPE_AGENT);
        }
    }

    // Pin the row's x in registers (no rematerialization from memory).
#pragma unroll
    for (int j = 0; j < 14; ++j)
        asm volatile("" : "+v"(xa[j]), "+v"(xb[j]), "+v"(xc[j]), "+v"(xd[j]));

    asm volatile("s_waitcnt vmcnt(0)" ::: "memory");     // stats stores complete
    __syncthreads();
    if (tid == 0)
        __hip_atomic_store(&flags[wid], 1, __ATOMIC_RELAXED, __HIP_MEMORY_SCOPE_AGENT);

    // ---- P2a: lane-parallel spin with s_sleep backoff ----------------------
    if (tid < 7) {
        int st = 0;                                      // own row
        if (tid != HALO) {
            const int rr = r - HALO + tid;
            if (rr < 0 || rr >= Hn) st = 2;              // zero-padding row
            else {
                const int f = wid - HALO + tid;
                int got = __hip_atomic_load(&flags[f], __ATOMIC_RELAXED,
                                            __HIP_MEMORY_SCOPE_AGENT);
                int it = 0;
                while (!got && ++it < SPIN_MAX) {
                    __builtin_amdgcn_s_sleep(16);        // ~1k clocks, frees SIMD
                    got = __hip_atomic_load(&flags[f], __ATOMIC_RELAXED,
                                            __HIP_MEMORY_SCOPE_AGENT);
                }
                st = got ? 1 : 3;
            }
        }
        rowstate[tid] = st;
    }
    __syncthreads();

    // ---- P2b: bulk-load published halo stats (relaxed u64 from MALL) -------
    for (int p = tid; p < 7 * Wn; p += 256) {
        const int kr = p / Wn;
        const int c  = p % Wn;
        if (rowstate[kr] == 1) {
            f2u t;
            t.u = __hip_atomic_load(&stats[(size_t)(wid - HALO + kr) * Wn + c],
                                    __ATOMIC_RELAXED, __HIP_MEMORY_SCOPE_AGENT);
            sdat[kr][c + HALO] = t.f;
        }
    }
    // ---- P2c: fallback recompute for unpublished rows (rare, correct) ------
    for (int kr = 0; kr < 7; ++kr) {
        if (rowstate[kr] != 3) continue;                 // uniform across block
        const int rr = r - HALO + kr;
        const size_t rb = ((size_t)(b * Hn + rr)) * Wn * 32;
        for (int pc = grp; pc < Wn; pc += 8) {
            const floatx4 v = x4[rb + (size_t)pc * 32 + lane];
            float s = v.x + v.y + v.z + v.w;
            float m = fmaxf(fmaxf(v.x, v.y), fmaxf(v.z, v.w));
#pragma unroll
            for (int off = 16; off >= 1; off >>= 1) {
                s += __shfl_xor(s, off);
                m = fmaxf(m, __shfl_xor(m, off));
            }
            if (lane == 0) sdat[kr][pc + HALO] = make_float2(s * (1.0f / 128.0f), m);
        }
    }
    __syncthreads();

    // ---- P3: 7x7 conv + bias + sigmoid -> gate ------------------------------
    if (tid < Wn) {
        float acc = bias[0];
#pragma unroll
        for (int kh = 0; kh < 7; ++kh)
#pragma unroll
            for (int kw = 0; kw < 7; ++kw) {
                const float2 sv = sdat[kh][tid + kw];
                acc = fmaf(sv.x, w[(kh * 7 + kw) * 2 + 0], acc);
                acc = fmaf(sv.y, w[(kh * 7 + kw) * 2 + 1], acc);
            }
        glds[tid] = 1.0f / (1.0f + expf(-acc));
    }
    __syncthreads();

    // ---- P4: out = x(reg) * gate, NT store (x never re-read) ---------------
    floatx4* __restrict__ o4 = reinterpret_cast<floatx4*>(out);
#pragma unroll
    for (int j = 0; j < 14; ++j) {
        const int c = grp + 8 * j;
        const float g = glds[c];
        floatx4 v;
        v.x = xa[j] * g; v.y = xb[j] * g; v.z = xc[j] * g; v.w = xd[j] * g;
        __builtin_nontemporal_store(v, &o4[rowbase + (size_t)c * 32 + lane]);
    }
}

extern "C" void kernel_launch(void* const* d_in, const int* in_sizes, int n_in,
                              void* d_out, int out_size, void* d_ws, size_t ws_size,
                              hipStream_t stream) {
    const float* x  = (const float*)d_in[0];
    const float* Wc = (const float*)d_in[1];
    const float* bb = (const float*)d_in[2];
    float* out = (float*)d_out;

    // workspace: stats u64[NROWS*Wn] (3.2 MB) then flags int[NROWS] (14 KB)
    unsigned long long* stats = (unsigned long long*)d_ws;
    int* flags = (int*)((char*)d_ws + (size_t)NROWS * Wn * sizeof(unsigned long long));

    hipMemsetAsync(flags, 0, NROWS * sizeof(int), stream);
    fused_reg_kernel<<<NROWS, 256, 0, stream>>>(x, Wc, bb, stats, flags, out);
}